// Round 14
// baseline (132.336 us; speedup 1.0000x reference)
//
#include <hip/hip_runtime.h>

typedef __bf16 bf16x8 __attribute__((ext_vector_type(8)));
typedef short short8 __attribute__((ext_vector_type(8)));
typedef float f32x4 __attribute__((ext_vector_type(4)));

// B=8, T=2048, E=512, H=8, d=64
#define TT 2048
#define EE 512
#define NH 8
#define DD 64

#define QSCALE 0.36067376022224085f   // 0.25 * log2(e)
#define CSCALE 0.18033688011112042f   // 0.125 * log2(e)

__device__ __forceinline__ ushort f2bf(float f) {
  union { float f; unsigned u; } a; a.f = f;
  unsigned u = a.u;
  return (ushort)((u + 0x7FFFu + ((u >> 16) & 1u)) >> 16);  // RNE
}

// ---------------- Kernel 1: fused LayerNorm + Q,K + transposed xnt ---------
// (R11 verbatim — measured good)
__global__ __launch_bounds__(1024) void k_lnt(
    const float* __restrict__ x, const float* __restrict__ Wq,
    const float* __restrict__ Wk,
    float* __restrict__ Q, float* __restrict__ K, ushort* __restrict__ xnt) {
  const int tid = threadIdx.x;
  const int wv = tid >> 6, l = tid & 63;
  const int t0 = blockIdx.x * 64;
  __shared__ ushort tile[64][520];

#pragma unroll
  for (int it = 0; it < 4; it++) {
    const int tl = wv * 4 + it;
    const int token = t0 + tl;
    const float* xr = x + (size_t)token * EE + l * 8;
    float4 a = *(const float4*)xr;
    float4 c = *(const float4*)(xr + 4);
    float xv[8] = {a.x, a.y, a.z, a.w, c.x, c.y, c.z, c.w};
    float s = 0.f, s2 = 0.f;
#pragma unroll
    for (int i = 0; i < 8; i++) { s += xv[i]; s2 = fmaf(xv[i], xv[i], s2); }
#pragma unroll
    for (int o = 32; o; o >>= 1) { s += __shfl_xor(s, o); s2 += __shfl_xor(s2, o); }
    const float mean = s * (1.f / 512.f);
    const float var = s2 * (1.f / 512.f) - mean * mean;
    const float rstd = rsqrtf(var + 1e-5f);

    float xn[8];
    short8 ob;
#pragma unroll
    for (int i = 0; i < 8; i++) {
      xn[i] = (xv[i] - mean) * rstd;
      ob[i] = (short)f2bf(xn[i]);
    }
    *(short8*)&tile[tl][l * 8] = ob;

    const float* wq = Wq + l * 8;
    const float* wk = Wk + l * 8;
    float4 q1 = *(const float4*)wq, q2 = *(const float4*)(wq + 4);
    float4 k1 = *(const float4*)wk, k2 = *(const float4*)(wk + 4);
    float wqv[8] = {q1.x, q1.y, q1.z, q1.w, q2.x, q2.y, q2.z, q2.w};
    float wkv[8] = {k1.x, k1.y, k1.z, k1.w, k2.x, k2.y, k2.z, k2.w};
    float q = 0.f, k = 0.f;
#pragma unroll
    for (int i = 0; i < 8; i++) { q = fmaf(xn[i], wqv[i], q); k = fmaf(xn[i], wkv[i], k); }
#pragma unroll
    for (int o = 4; o; o >>= 1) { q += __shfl_xor(q, o); k += __shfl_xor(k, o); }
    if ((l & 7) == 0) {
      const int h = l >> 3;
      const int b = token >> 11, t = token & (TT - 1);
      const int bh = b * NH + h;
      Q[bh * TT + t] = q * QSCALE;
      K[bh * TT + t] = k;
    }
  }
  __syncthreads();

  {
    const int h = tid >> 7, e = (tid >> 1) & 63, half = tid & 1;
    const int b = t0 >> 11, trow = t0 & (TT - 1);
    const int col = h * 64 + e;
    ushort* rowp = xnt + (size_t)((b * NH + h) * DD + e) * TT + trow;
#pragma unroll
    for (int ch = 0; ch < 4; ch++) {
      const int c_idx = half * 4 + ch;
      union { uint4 v; ushort u[8]; } o;
#pragma unroll
      for (int i = 0; i < 8; i++) o.u[i] = tile[c_idx * 8 + i][col];
      *(uint4*)(rowp + (((c_idx ^ (e & 7)) << 3))) = o.v;
    }
  }
}

// ---------------- Kernel 2: Wvmt[n][k] = (Wv_h @ Wm_h)^T, bf16 -------------
__global__ __launch_bounds__(256) void k_wvm(
    const float* __restrict__ Wv, const float* __restrict__ Wm,
    ushort* __restrict__ Wvmt) {
  const int k = blockIdx.x;
  const int h = k >> 6;
  const int tid = threadIdx.x;
  __shared__ float wv[64];
  if (tid < 64) wv[tid] = Wv[k * 64 + tid];
  __syncthreads();
  float a0 = 0.f, a1 = 0.f;
#pragma unroll 8
  for (int e = 0; e < 64; e++) {
    const float w = wv[e];
    const float* row = Wm + (size_t)(h * 64 + e) * EE;
    a0 = fmaf(w, row[tid], a0);
    a1 = fmaf(w, row[tid + 256], a1);
  }
  Wvmt[(size_t)tid * EE + k] = f2bf(a0);
  Wvmt[(size_t)(tid + 256) * EE + k] = f2bf(a1);
}

// ---------------- Kernel 3: distance attention (R11 verbatim, 60.2 µs) -----
__global__ __launch_bounds__(256, 2) void k_attn(
    const float* __restrict__ Q, const float* __restrict__ K,
    const ushort* __restrict__ xnt, ushort* __restrict__ hr) {
  const int sw = (blockIdx.x & 7) * 64 + (blockIdx.x >> 3);  // bijective XCD swizzle
  const int bh = sw >> 3;
  const int q0 = (sw & 7) * 256;
  const int b = bh >> 3, h = bh & 7;
  const int tid = threadIdx.x;
  const int w = tid >> 6, l = tid & 63;
  const int l16 = l & 15, lhi = l >> 4;

  __shared__ float ks[TT];
  __shared__ float cs[TT];
  __shared__ ushort vt[2][64 * 64];

  {
    const float* Kb = K + bh * TT;
#pragma unroll
    for (int i = 0; i < 8; i++) {
      float kv = Kb[tid + i * 256];
      ks[tid + i * 256] = kv;
      cs[tid + i * 256] = -kv * kv * CSCALE;
    }
  }

  const ushort* Xs = xnt + (size_t)bh * (DD * TT);
  const int se = tid >> 3;
  const int sc = (tid & 7) * 8;
  uint4 st0, st1;

#define ISSUE_STAGE(jt_) do {                                                  \
    st0 = *(const uint4*)(Xs + (size_t)se * TT + (jt_) + sc);                  \
    st1 = *(const uint4*)(Xs + (size_t)(se + 32) * TT + (jt_) + sc);           \
  } while (0)

#define WRITE_STAGE(buf_) do {                                                 \
    *(uint4*)&vt[buf_][se * 64 + sc] = st0;                                    \
    *(uint4*)&vt[buf_][(se + 32) * 64 + sc] = st1;                             \
  } while (0)

  ISSUE_STAGE(0);
  WRITE_STAGE(0);
  __syncthreads();

  float qv[4];
#pragma unroll
  for (int f = 0; f < 4; f++) qv[f] = Q[bh * TT + q0 + w * 64 + f * 16 + l16];

  f32x4 acc[4][4];
  f32x4 accd[4];
#pragma unroll
  for (int f = 0; f < 4; f++) {
    accd[f] = (f32x4){0.f, 0.f, 0.f, 0.f};
#pragma unroll
    for (int c = 0; c < 4; c++) acc[f][c] = (f32x4){0.f, 0.f, 0.f, 0.f};
  }
  short8 onesbits = {0x3F80, 0x3F80, 0x3F80, 0x3F80, 0x3F80, 0x3F80, 0x3F80, 0x3F80};
  const bf16x8 ones = __builtin_bit_cast(bf16x8, onesbits);

  int p = 0;
  for (int jt = 0; jt < TT; jt += 64) {
    const bool more = (jt + 64) < TT;
    if (more) ISSUE_STAGE(jt + 64);   // issue-early

    __builtin_amdgcn_s_setprio(1);
#pragma unroll
    for (int kk = 0; kk < 2; kk++) {
      bf16x8 vf[4];
#pragma unroll
      for (int c = 0; c < 4; c++) {
        const int e = c * 16 + l16;
        vf[c] = *(const bf16x8*)&vt[p][e * 64 + (((kk * 4 + lhi) ^ (e & 7)) << 3)];
      }
      const int jb = jt + kk * 32 + lhi * 8;
      float4 ka = *(const float4*)&ks[jb];
      float4 kb2 = *(const float4*)&ks[jb + 4];
      float4 ca = *(const float4*)&cs[jb];
      float4 cb2 = *(const float4*)&cs[jb + 4];
      float kv8[8] = {ka.x, ka.y, ka.z, ka.w, kb2.x, kb2.y, kb2.z, kb2.w};
      float cv8[8] = {ca.x, ca.y, ca.z, ca.w, cb2.x, cb2.y, cb2.z, cb2.w};
#pragma unroll
      for (int f = 0; f < 4; f++) {
        bf16x8 pa;
#pragma unroll
        for (int i = 0; i < 8; i++)
          pa[i] = (__bf16)__builtin_amdgcn_exp2f(fmaf(qv[f], kv8[i], cv8[i]));
        accd[f] = __builtin_amdgcn_mfma_f32_16x16x32_bf16(pa, ones, accd[f], 0, 0, 0);
#pragma unroll
        for (int c = 0; c < 4; c++)
          acc[f][c] = __builtin_amdgcn_mfma_f32_16x16x32_bf16(pa, vf[c], acc[f][c], 0, 0, 0);
      }
    }
    __builtin_amdgcn_s_setprio(0);

    if (more) WRITE_STAGE(p ^ 1);     // write-late
    __syncthreads();
    p ^= 1;
  }
#undef ISSUE_STAGE
#undef WRITE_STAGE

#pragma unroll
  for (int f = 0; f < 4; f++) {
#pragma unroll
    for (int r = 0; r < 4; r++) {
      const float rinv = 1.f / accd[f][r];
      const int qrow = q0 + w * 64 + f * 16 + lhi * 4 + r;
      const size_t base = ((size_t)(b * TT + qrow)) * EE + h * DD + l16;
#pragma unroll
      for (int c = 0; c < 4; c++)
        hr[base + c * 16] = f2bf(acc[f][c][r] * rinv);
    }
  }
}

// ---------------- Kernel 4: out = hr @ Wvm + x  (bf16 MFMA GEMM) -----------
// Tile 64x128, grid (4, 256) = 1024 blocks -> 3 blocks/CU (LDS 48 KB, lb(256,3)).
// XOR-chunk-swizzled stride-64 LDS (attn-proven pattern, no padding);
// lane-major contiguous staging; XCD-grouped remap; direct stores (R11-proven).
__global__ __launch_bounds__(256, 3) void k_merge(
    const ushort* __restrict__ hr, const ushort* __restrict__ Wmt,
    const float* __restrict__ x, float* __restrict__ out) {
  const int fid = blockIdx.y * 4 + blockIdx.x;   // 0..1023, x fastest
  const int xcd = fid & 7, idx = fid >> 3;       // idx 0..127
  const int n0 = (idx & 3) * 128;
  const int m0 = (xcd * 32 + (idx >> 2)) * 64;   // each XCD: 32 m-strips x 4 n
  const int tid = threadIdx.x;
  const int w = tid >> 6, l = tid & 63;
  const int l16 = l & 15, lhi = l >> 4;
  const int wm = w >> 1, wn = w & 1;             // wave tile: 32m x 64n

  __shared__ ushort As[2][64 * 64];              // 16 KB
  __shared__ ushort Bs[2][128 * 64];             // 32 KB

  f32x4 acc[2][4];
#pragma unroll
  for (int i = 0; i < 2; i++)
#pragma unroll
    for (int j = 0; j < 4; j++) acc[i][j] = (f32x4){0.f, 0.f, 0.f, 0.f};

  const ushort* ha = hr + (size_t)m0 * EE;
  const ushort* wb = Wmt + (size_t)n0 * EE;
  uint4 pa[2], pb[4];

  // lane-major staging ids: A id = i*256+tid (i<2): row=id>>3, ch=id&7
  //                         B id = i*256+tid (i<4)
#define STAGE_ISSUE(k0_) do {                                                  \
    _Pragma("unroll") for (int i = 0; i < 2; i++) {                            \
      const int id = i * 256 + tid;                                            \
      pa[i] = *(const uint4*)(ha + (size_t)(id >> 3) * EE + (k0_) + (id & 7) * 8); \
    }                                                                          \
    _Pragma("unroll") for (int i = 0; i < 4; i++) {                            \
      const int id = i * 256 + tid;                                            \
      pb[i] = *(const uint4*)(wb + (size_t)(id >> 3) * EE + (k0_) + (id & 7) * 8); \
    }                                                                          \
  } while (0)

#define STAGE_WRITE(p_) do {                                                   \
    _Pragma("unroll") for (int i = 0; i < 2; i++) {                            \
      const int id = i * 256 + tid;                                            \
      const int row = id >> 3, ch = id & 7;                                    \
      *(uint4*)&As[p_][row * 64 + ((ch ^ (row & 7)) << 3)] = pa[i];            \
    }                                                                          \
    _Pragma("unroll") for (int i = 0; i < 4; i++) {                            \
      const int id = i * 256 + tid;                                            \
      const int row = id >> 3, ch = id & 7;                                    \
      *(uint4*)&Bs[p_][row * 64 + ((ch ^ (row & 7)) << 3)] = pb[i];            \
    }                                                                          \
  } while (0)

  STAGE_ISSUE(0);
  STAGE_WRITE(0);
  __syncthreads();

  int p = 0;
  for (int k0 = 0; k0 < EE; k0 += 64) {
    const bool more = (k0 + 64) < EE;
    if (more) STAGE_ISSUE(k0 + 64);   // issue-early

#pragma unroll
    for (int kk = 0; kk < 2; kk++) {
      bf16x8 af[2], bfr[4];
#pragma unroll
      for (int mi = 0; mi < 2; mi++) {
        const int row = wm * 32 + mi * 16 + l16;
        af[mi] = *(const bf16x8*)&As[p][row * 64 + (((kk * 4 + lhi) ^ (row & 7)) << 3)];
      }
#pragma unroll
      for (int ni = 0; ni < 4; ni++) {
        const int row = wn * 64 + ni * 16 + l16;
        bfr[ni] = *(const bf16x8*)&Bs[p][row * 64 + (((kk * 4 + lhi) ^ (row & 7)) << 3)];
      }
#pragma unroll
      for (int mi = 0; mi < 2; mi++)
#pragma unroll
        for (int ni = 0; ni < 4; ni++)
          acc[mi][ni] = __builtin_amdgcn_mfma_f32_16x16x32_bf16(af[mi], bfr[ni], acc[mi][ni], 0, 0, 0);
    }

    if (more) STAGE_WRITE(p ^ 1);     // write-late
    __syncthreads();
    p ^= 1;
  }
#undef STAGE_ISSUE
#undef STAGE_WRITE

#pragma unroll
  for (int mi = 0; mi < 2; mi++) {
#pragma unroll
    for (int r = 0; r < 4; r++) {
      const int grow = m0 + wm * 32 + mi * 16 + lhi * 4 + r;
#pragma unroll
      for (int ni = 0; ni < 4; ni++) {
        const int gcol = n0 + wn * 64 + ni * 16 + l16;
        size_t idx2 = (size_t)grow * EE + gcol;
        out[idx2] = acc[mi][ni][r] + x[idx2];
      }
    }
  }
}

// ---------------- launch ----------------------------------------------------
extern "C" void kernel_launch(void* const* d_in, const int* in_sizes, int n_in,
                              void* d_out, int out_size, void* d_ws, size_t ws_size,
                              hipStream_t stream) {
  const float* x  = (const float*)d_in[0];
  const float* Wq = (const float*)d_in[1];
  const float* Wk = (const float*)d_in[2];
  const float* Wv = (const float*)d_in[3];
  const float* Wm = (const float*)d_in[4];
  float* out = (float*)d_out;

  char* ws = (char*)d_ws;
  float*  Qp   = (float*)(ws);
  float*  Kp   = (float*)(ws + 524288);
  ushort* hrp  = (ushort*)(ws + 1048576);
  ushort* xnt  = (ushort*)(ws + 17825792);
  ushort* Wvmt = (ushort*)(ws + 34603008);

  k_lnt<<<256, 1024, 0, stream>>>(x, Wq, Wk, Qp, Kp, xnt);
  k_wvm<<<EE, 256, 0, stream>>>(Wv, Wm, Wvmt);
  k_attn<<<512, 256, 0, stream>>>(Qp, Kp, xnt, hrp);
  k_merge<<<dim3(EE / 128, (8 * TT) / 64), 256, 0, stream>>>(hrp, Wvmt, x, out);
}

// Round 15
// 121.666 us; speedup vs baseline: 1.0877x; 1.0877x over previous
//
#include <hip/hip_runtime.h>

typedef __bf16 bf16x8 __attribute__((ext_vector_type(8)));
typedef short short8 __attribute__((ext_vector_type(8)));
typedef float f32x4 __attribute__((ext_vector_type(4)));

// B=8, T=2048, E=512, H=8, d=64
#define TT 2048
#define EE 512
#define NH 8
#define DD 64

#define QSCALE 0.36067376022224085f   // 0.25 * log2(e)
#define CSCALE 0.18033688011112042f   // 0.125 * log2(e)

__device__ __forceinline__ ushort f2bf(float f) {
  union { float f; unsigned u; } a; a.f = f;
  unsigned u = a.u;
  return (ushort)((u + 0x7FFFu + ((u >> 16) & 1u)) >> 16);  // RNE
}

// ---------------- Kernel 1: fused LayerNorm + Q,K + transposed xnt ---------
// (R11 verbatim — measured good)
__global__ __launch_bounds__(1024) void k_lnt(
    const float* __restrict__ x, const float* __restrict__ Wq,
    const float* __restrict__ Wk,
    float* __restrict__ Q, float* __restrict__ K, ushort* __restrict__ xnt) {
  const int tid = threadIdx.x;
  const int wv = tid >> 6, l = tid & 63;
  const int t0 = blockIdx.x * 64;
  __shared__ ushort tile[64][520];

#pragma unroll
  for (int it = 0; it < 4; it++) {
    const int tl = wv * 4 + it;
    const int token = t0 + tl;
    const float* xr = x + (size_t)token * EE + l * 8;
    float4 a = *(const float4*)xr;
    float4 c = *(const float4*)(xr + 4);
    float xv[8] = {a.x, a.y, a.z, a.w, c.x, c.y, c.z, c.w};
    float s = 0.f, s2 = 0.f;
#pragma unroll
    for (int i = 0; i < 8; i++) { s += xv[i]; s2 = fmaf(xv[i], xv[i], s2); }
#pragma unroll
    for (int o = 32; o; o >>= 1) { s += __shfl_xor(s, o); s2 += __shfl_xor(s2, o); }
    const float mean = s * (1.f / 512.f);
    const float var = s2 * (1.f / 512.f) - mean * mean;
    const float rstd = rsqrtf(var + 1e-5f);

    float xn[8];
    short8 ob;
#pragma unroll
    for (int i = 0; i < 8; i++) {
      xn[i] = (xv[i] - mean) * rstd;
      ob[i] = (short)f2bf(xn[i]);
    }
    *(short8*)&tile[tl][l * 8] = ob;

    const float* wq = Wq + l * 8;
    const float* wk = Wk + l * 8;
    float4 q1 = *(const float4*)wq, q2 = *(const float4*)(wq + 4);
    float4 k1 = *(const float4*)wk, k2 = *(const float4*)(wk + 4);
    float wqv[8] = {q1.x, q1.y, q1.z, q1.w, q2.x, q2.y, q2.z, q2.w};
    float wkv[8] = {k1.x, k1.y, k1.z, k1.w, k2.x, k2.y, k2.z, k2.w};
    float q = 0.f, k = 0.f;
#pragma unroll
    for (int i = 0; i < 8; i++) { q = fmaf(xn[i], wqv[i], q); k = fmaf(xn[i], wkv[i], k); }
#pragma unroll
    for (int o = 4; o; o >>= 1) { q += __shfl_xor(q, o); k += __shfl_xor(k, o); }
    if ((l & 7) == 0) {
      const int h = l >> 3;
      const int b = token >> 11, t = token & (TT - 1);
      const int bh = b * NH + h;
      Q[bh * TT + t] = q * QSCALE;
      K[bh * TT + t] = k;
    }
  }
  __syncthreads();

  {
    const int h = tid >> 7, e = (tid >> 1) & 63, half = tid & 1;
    const int b = t0 >> 11, trow = t0 & (TT - 1);
    const int col = h * 64 + e;
    ushort* rowp = xnt + (size_t)((b * NH + h) * DD + e) * TT + trow;
#pragma unroll
    for (int ch = 0; ch < 4; ch++) {
      const int c_idx = half * 4 + ch;
      union { uint4 v; ushort u[8]; } o;
#pragma unroll
      for (int i = 0; i < 8; i++) o.u[i] = tile[c_idx * 8 + i][col];
      *(uint4*)(rowp + (((c_idx ^ (e & 7)) << 3))) = o.v;
    }
  }
}

// ---------------- Kernel 2: Wvmt[n][k] = (Wv_h @ Wm_h)^T, bf16 -------------
__global__ __launch_bounds__(256) void k_wvm(
    const float* __restrict__ Wv, const float* __restrict__ Wm,
    ushort* __restrict__ Wvmt) {
  const int k = blockIdx.x;
  const int h = k >> 6;
  const int tid = threadIdx.x;
  __shared__ float wv[64];
  if (tid < 64) wv[tid] = Wv[k * 64 + tid];
  __syncthreads();
  float a0 = 0.f, a1 = 0.f;
#pragma unroll 8
  for (int e = 0; e < 64; e++) {
    const float w = wv[e];
    const float* row = Wm + (size_t)(h * 64 + e) * EE;
    a0 = fmaf(w, row[tid], a0);
    a1 = fmaf(w, row[tid + 256], a1);
  }
  Wvmt[(size_t)tid * EE + k] = f2bf(a0);
  Wvmt[(size_t)(tid + 256) * EE + k] = f2bf(a1);
}

// ---------------- Kernel 3: distance attention (R11 verbatim, 60.2 µs) -----
__global__ __launch_bounds__(256, 2) void k_attn(
    const float* __restrict__ Q, const float* __restrict__ K,
    const ushort* __restrict__ xnt, ushort* __restrict__ hr) {
  const int sw = (blockIdx.x & 7) * 64 + (blockIdx.x >> 3);  // bijective XCD swizzle
  const int bh = sw >> 3;
  const int q0 = (sw & 7) * 256;
  const int b = bh >> 3, h = bh & 7;
  const int tid = threadIdx.x;
  const int w = tid >> 6, l = tid & 63;
  const int l16 = l & 15, lhi = l >> 4;

  __shared__ float ks[TT];
  __shared__ float cs[TT];
  __shared__ ushort vt[2][64 * 64];

  {
    const float* Kb = K + bh * TT;
#pragma unroll
    for (int i = 0; i < 8; i++) {
      float kv = Kb[tid + i * 256];
      ks[tid + i * 256] = kv;
      cs[tid + i * 256] = -kv * kv * CSCALE;
    }
  }

  const ushort* Xs = xnt + (size_t)bh * (DD * TT);
  const int se = tid >> 3;
  const int sc = (tid & 7) * 8;
  uint4 st0, st1;

#define ISSUE_STAGE(jt_) do {                                                  \
    st0 = *(const uint4*)(Xs + (size_t)se * TT + (jt_) + sc);                  \
    st1 = *(const uint4*)(Xs + (size_t)(se + 32) * TT + (jt_) + sc);           \
  } while (0)

#define WRITE_STAGE(buf_) do {                                                 \
    *(uint4*)&vt[buf_][se * 64 + sc] = st0;                                    \
    *(uint4*)&vt[buf_][(se + 32) * 64 + sc] = st1;                             \
  } while (0)

  ISSUE_STAGE(0);
  WRITE_STAGE(0);
  __syncthreads();

  float qv[4];
#pragma unroll
  for (int f = 0; f < 4; f++) qv[f] = Q[bh * TT + q0 + w * 64 + f * 16 + l16];

  f32x4 acc[4][4];
  f32x4 accd[4];
#pragma unroll
  for (int f = 0; f < 4; f++) {
    accd[f] = (f32x4){0.f, 0.f, 0.f, 0.f};
#pragma unroll
    for (int c = 0; c < 4; c++) acc[f][c] = (f32x4){0.f, 0.f, 0.f, 0.f};
  }
  short8 onesbits = {0x3F80, 0x3F80, 0x3F80, 0x3F80, 0x3F80, 0x3F80, 0x3F80, 0x3F80};
  const bf16x8 ones = __builtin_bit_cast(bf16x8, onesbits);

  int p = 0;
  for (int jt = 0; jt < TT; jt += 64) {
    const bool more = (jt + 64) < TT;
    if (more) ISSUE_STAGE(jt + 64);   // issue-early

    __builtin_amdgcn_s_setprio(1);
#pragma unroll
    for (int kk = 0; kk < 2; kk++) {
      bf16x8 vf[4];
#pragma unroll
      for (int c = 0; c < 4; c++) {
        const int e = c * 16 + l16;
        vf[c] = *(const bf16x8*)&vt[p][e * 64 + (((kk * 4 + lhi) ^ (e & 7)) << 3)];
      }
      const int jb = jt + kk * 32 + lhi * 8;
      float4 ka = *(const float4*)&ks[jb];
      float4 kb2 = *(const float4*)&ks[jb + 4];
      float4 ca = *(const float4*)&cs[jb];
      float4 cb2 = *(const float4*)&cs[jb + 4];
      float kv8[8] = {ka.x, ka.y, ka.z, ka.w, kb2.x, kb2.y, kb2.z, kb2.w};
      float cv8[8] = {ca.x, ca.y, ca.z, ca.w, cb2.x, cb2.y, cb2.z, cb2.w};
#pragma unroll
      for (int f = 0; f < 4; f++) {
        bf16x8 pa;
#pragma unroll
        for (int i = 0; i < 8; i++)
          pa[i] = (__bf16)__builtin_amdgcn_exp2f(fmaf(qv[f], kv8[i], cv8[i]));
        accd[f] = __builtin_amdgcn_mfma_f32_16x16x32_bf16(pa, ones, accd[f], 0, 0, 0);
#pragma unroll
        for (int c = 0; c < 4; c++)
          acc[f][c] = __builtin_amdgcn_mfma_f32_16x16x32_bf16(pa, vf[c], acc[f][c], 0, 0, 0);
      }
    }
    __builtin_amdgcn_s_setprio(0);

    if (more) WRITE_STAGE(p ^ 1);     // write-late
    __syncthreads();
    p ^= 1;
  }
#undef ISSUE_STAGE
#undef WRITE_STAGE

#pragma unroll
  for (int f = 0; f < 4; f++) {
#pragma unroll
    for (int r = 0; r < 4; r++) {
      const float rinv = 1.f / accd[f][r];
      const int qrow = q0 + w * 64 + f * 16 + lhi * 4 + r;
      const size_t base = ((size_t)(b * TT + qrow)) * EE + h * DD + l16;
#pragma unroll
      for (int c = 0; c < 4; c++)
        hr[base + c * 16] = f2bf(acc[f][c][r] * rinv);
    }
  }
}

// ---------------- Kernel 4: out = hr @ Wvm + x  (bf16 MFMA GEMM) -----------
// R11 structure (128x128 tile, 4 waves 2x2, dbuf LDS stride-72, XCD-grouped
// remap) with SWAPPED MFMA operands: mfma(bfr, af) -> D row = n, col = m.
// Each acc f32x4 then spans 4 CONSECUTIVE out columns -> float4 epilogue
// (16B RMW per acc, 4x fewer epilogue instructions, no LDS bounce).
__global__ __launch_bounds__(256, 2) void k_merge(
    const ushort* __restrict__ hr, const ushort* __restrict__ Wmt,
    const float* __restrict__ x, float* __restrict__ out) {
  const int fid = blockIdx.y * 4 + blockIdx.x;   // dispatch order (x fastest)
  const int xcd = fid & 7, idx = fid >> 3;
  const int n0 = (idx & 3) * 128;
  const int m0 = (xcd * 16 + (idx >> 2)) * 128;
  const int tid = threadIdx.x;
  const int w = tid >> 6, l = tid & 63;
  const int l16 = l & 15, lhi = l >> 4;
  const int wm = w >> 1, wn = w & 1;

  __shared__ ushort As[2][128 * 72];
  __shared__ ushort Bs[2][128 * 72];
  f32x4 acc[4][4];
#pragma unroll
  for (int i = 0; i < 4; i++)
#pragma unroll
    for (int j = 0; j < 4; j++) acc[i][j] = (f32x4){0.f, 0.f, 0.f, 0.f};

  const int row = tid >> 1, half = tid & 1;
  const ushort* sa0 = hr + (size_t)(m0 + row) * EE + half * 32;
  const ushort* sb0 = Wmt + (size_t)(n0 + row) * EE + half * 32;

  {
    uint4* da = (uint4*)&As[0][row * 72 + half * 32];
    uint4* db = (uint4*)&Bs[0][row * 72 + half * 32];
#pragma unroll
    for (int i = 0; i < 4; i++) da[i] = *(const uint4*)(sa0 + i * 8);
#pragma unroll
    for (int i = 0; i < 4; i++) db[i] = *(const uint4*)(sb0 + i * 8);
  }
  __syncthreads();

  int p = 0;
  for (int k0 = 0; k0 < EE; k0 += 64) {
    const bool more = (k0 + 64) < EE;
    uint4 pa[4], pb[4];
    if (more) {
#pragma unroll
      for (int i = 0; i < 4; i++) pa[i] = *(const uint4*)(sa0 + k0 + 64 + i * 8);
#pragma unroll
      for (int i = 0; i < 4; i++) pb[i] = *(const uint4*)(sb0 + k0 + 64 + i * 8);
    }
#pragma unroll
    for (int kk = 0; kk < 2; kk++) {
      bf16x8 af[4], bfr[4];
#pragma unroll
      for (int mi = 0; mi < 4; mi++)
        af[mi] = *(const bf16x8*)&As[p][(wm * 64 + mi * 16 + l16) * 72 + kk * 32 + lhi * 8];
#pragma unroll
      for (int ni = 0; ni < 4; ni++)
        bfr[ni] = *(const bf16x8*)&Bs[p][(wn * 64 + ni * 16 + l16) * 72 + kk * 32 + lhi * 8];
#pragma unroll
      for (int mi = 0; mi < 4; mi++)
#pragma unroll
        for (int ni = 0; ni < 4; ni++)
          acc[mi][ni] = __builtin_amdgcn_mfma_f32_16x16x32_bf16(bfr[ni], af[mi], acc[mi][ni], 0, 0, 0);
    }
    if (more) {
      uint4* da = (uint4*)&As[p ^ 1][row * 72 + half * 32];
      uint4* db = (uint4*)&Bs[p ^ 1][row * 72 + half * 32];
#pragma unroll
      for (int i = 0; i < 4; i++) da[i] = pa[i];
#pragma unroll
      for (int i = 0; i < 4; i++) db[i] = pb[i];
    }
    __syncthreads();
    p ^= 1;
  }

  // epilogue: D row = n (bfr index), col = m (af index):
  //   grow = m0 + wm*64 + mi*16 + l16   (fixed per lane)
  //   gcol = n0 + wn*64 + ni*16 + lhi*4 + r  -> r is contiguous: float4 RMW
#pragma unroll
  for (int mi = 0; mi < 4; mi++) {
    const int grow = m0 + wm * 64 + mi * 16 + l16;
    const float* xr = x + (size_t)grow * EE;
    float* og = out + (size_t)grow * EE;
#pragma unroll
    for (int ni = 0; ni < 4; ni++) {
      const int gcol = n0 + wn * 64 + ni * 16 + lhi * 4;
      float4 xa = *(const float4*)(xr + gcol);
      f32x4 v = acc[mi][ni];
      float4 o = {v[0] + xa.x, v[1] + xa.y, v[2] + xa.z, v[3] + xa.w};
      *(float4*)(og + gcol) = o;
    }
  }
}

// ---------------- launch ----------------------------------------------------
extern "C" void kernel_launch(void* const* d_in, const int* in_sizes, int n_in,
                              void* d_out, int out_size, void* d_ws, size_t ws_size,
                              hipStream_t stream) {
  const float* x  = (const float*)d_in[0];
  const float* Wq = (const float*)d_in[1];
  const float* Wk = (const float*)d_in[2];
  const float* Wv = (const float*)d_in[3];
  const float* Wm = (const float*)d_in[4];
  float* out = (float*)d_out;

  char* ws = (char*)d_ws;
  float*  Qp   = (float*)(ws);
  float*  Kp   = (float*)(ws + 524288);
  ushort* hrp  = (ushort*)(ws + 1048576);
  ushort* xnt  = (ushort*)(ws + 17825792);
  ushort* Wvmt = (ushort*)(ws + 34603008);

  k_lnt<<<256, 1024, 0, stream>>>(x, Wq, Wk, Qp, Kp, xnt);
  k_wvm<<<EE, 256, 0, stream>>>(Wv, Wm, Wvmt);
  k_attn<<<512, 256, 0, stream>>>(Qp, Kp, xnt, hrp);
  k_merge<<<dim3(EE / 128, (8 * TT) / 128), 256, 0, stream>>>(hrp, Wvmt, x, out);
}

// Round 16
// 120.157 us; speedup vs baseline: 1.1014x; 1.0126x over previous
//
#include <hip/hip_runtime.h>

typedef __bf16 bf16x8 __attribute__((ext_vector_type(8)));
typedef short short8 __attribute__((ext_vector_type(8)));
typedef float f32x4 __attribute__((ext_vector_type(4)));

// B=8, T=2048, E=512, H=8, d=64
#define TT 2048
#define EE 512
#define NH 8
#define DD 64

#define QSCALE 0.36067376022224085f   // 0.25 * log2(e)
#define CSCALE 0.18033688011112042f   // 0.125 * log2(e)

__device__ __forceinline__ ushort f2bf(float f) {
  union { float f; unsigned u; } a; a.f = f;
  unsigned u = a.u;
  return (ushort)((u + 0x7FFFu + ((u >> 16) & 1u)) >> 16);  // RNE
}

// ---------------- Kernel 1: fused LayerNorm + Q,K + transposed xnt ---------
// (R11 verbatim — measured good)
__global__ __launch_bounds__(1024) void k_lnt(
    const float* __restrict__ x, const float* __restrict__ Wq,
    const float* __restrict__ Wk,
    float* __restrict__ Q, float* __restrict__ K, ushort* __restrict__ xnt) {
  const int tid = threadIdx.x;
  const int wv = tid >> 6, l = tid & 63;
  const int t0 = blockIdx.x * 64;
  __shared__ ushort tile[64][520];

#pragma unroll
  for (int it = 0; it < 4; it++) {
    const int tl = wv * 4 + it;
    const int token = t0 + tl;
    const float* xr = x + (size_t)token * EE + l * 8;
    float4 a = *(const float4*)xr;
    float4 c = *(const float4*)(xr + 4);
    float xv[8] = {a.x, a.y, a.z, a.w, c.x, c.y, c.z, c.w};
    float s = 0.f, s2 = 0.f;
#pragma unroll
    for (int i = 0; i < 8; i++) { s += xv[i]; s2 = fmaf(xv[i], xv[i], s2); }
#pragma unroll
    for (int o = 32; o; o >>= 1) { s += __shfl_xor(s, o); s2 += __shfl_xor(s2, o); }
    const float mean = s * (1.f / 512.f);
    const float var = s2 * (1.f / 512.f) - mean * mean;
    const float rstd = rsqrtf(var + 1e-5f);

    float xn[8];
    short8 ob;
#pragma unroll
    for (int i = 0; i < 8; i++) {
      xn[i] = (xv[i] - mean) * rstd;
      ob[i] = (short)f2bf(xn[i]);
    }
    *(short8*)&tile[tl][l * 8] = ob;

    const float* wq = Wq + l * 8;
    const float* wk = Wk + l * 8;
    float4 q1 = *(const float4*)wq, q2 = *(const float4*)(wq + 4);
    float4 k1 = *(const float4*)wk, k2 = *(const float4*)(wk + 4);
    float wqv[8] = {q1.x, q1.y, q1.z, q1.w, q2.x, q2.y, q2.z, q2.w};
    float wkv[8] = {k1.x, k1.y, k1.z, k1.w, k2.x, k2.y, k2.z, k2.w};
    float q = 0.f, k = 0.f;
#pragma unroll
    for (int i = 0; i < 8; i++) { q = fmaf(xn[i], wqv[i], q); k = fmaf(xn[i], wkv[i], k); }
#pragma unroll
    for (int o = 4; o; o >>= 1) { q += __shfl_xor(q, o); k += __shfl_xor(k, o); }
    if ((l & 7) == 0) {
      const int h = l >> 3;
      const int b = token >> 11, t = token & (TT - 1);
      const int bh = b * NH + h;
      Q[bh * TT + t] = q * QSCALE;
      K[bh * TT + t] = k;
    }
  }
  __syncthreads();

  {
    const int h = tid >> 7, e = (tid >> 1) & 63, half = tid & 1;
    const int b = t0 >> 11, trow = t0 & (TT - 1);
    const int col = h * 64 + e;
    ushort* rowp = xnt + (size_t)((b * NH + h) * DD + e) * TT + trow;
#pragma unroll
    for (int ch = 0; ch < 4; ch++) {
      const int c_idx = half * 4 + ch;
      union { uint4 v; ushort u[8]; } o;
#pragma unroll
      for (int i = 0; i < 8; i++) o.u[i] = tile[c_idx * 8 + i][col];
      *(uint4*)(rowp + (((c_idx ^ (e & 7)) << 3))) = o.v;
    }
  }
}

// ---------------- Kernel 2: Wvmt[n][k] = (Wv_h @ Wm_h)^T, bf16 -------------
__global__ __launch_bounds__(256) void k_wvm(
    const float* __restrict__ Wv, const float* __restrict__ Wm,
    ushort* __restrict__ Wvmt) {
  const int k = blockIdx.x;
  const int h = k >> 6;
  const int tid = threadIdx.x;
  __shared__ float wv[64];
  if (tid < 64) wv[tid] = Wv[k * 64 + tid];
  __syncthreads();
  float a0 = 0.f, a1 = 0.f;
#pragma unroll 8
  for (int e = 0; e < 64; e++) {
    const float w = wv[e];
    const float* row = Wm + (size_t)(h * 64 + e) * EE;
    a0 = fmaf(w, row[tid], a0);
    a1 = fmaf(w, row[tid + 256], a1);
  }
  Wvmt[(size_t)tid * EE + k] = f2bf(a0);
  Wvmt[(size_t)(tid + 256) * EE + k] = f2bf(a1);
}

// ---------------- Kernel 3: distance attention, 2-tile barrier periods -----
// R11 body with barriers halved (17 vs 33): each period stages TWO 64-j
// tiles into the next dbuf set while computing the current set, never
// holding more than 2 uint4 (8 VGPRs) — R11-identical register pressure.
__global__ __launch_bounds__(256, 2) void k_attn(
    const float* __restrict__ Q, const float* __restrict__ K,
    const ushort* __restrict__ xnt, ushort* __restrict__ hr) {
  const int sw = (blockIdx.x & 7) * 64 + (blockIdx.x >> 3);  // bijective XCD swizzle
  const int bh = sw >> 3;
  const int q0 = (sw & 7) * 256;
  const int b = bh >> 3, h = bh & 7;
  const int tid = threadIdx.x;
  const int w = tid >> 6, l = tid & 63;
  const int l16 = l & 15, lhi = l >> 4;

  __shared__ float ks[TT];
  __shared__ float cs[TT];
  __shared__ ushort vt[2][2][64 * 64];   // [set][tile] 32 KB

  {
    const float* Kb = K + bh * TT;
#pragma unroll
    for (int i = 0; i < 8; i++) {
      float kv = Kb[tid + i * 256];
      ks[tid + i * 256] = kv;
      cs[tid + i * 256] = -kv * kv * CSCALE;
    }
  }

  const ushort* Xs = xnt + (size_t)bh * (DD * TT);
  const int se = tid >> 3;
  const int sc = (tid & 7) * 8;
  uint4 st0, st1;

#define ISSUE_STAGE(jt_) do {                                                  \
    st0 = *(const uint4*)(Xs + (size_t)se * TT + (jt_) + sc);                  \
    st1 = *(const uint4*)(Xs + (size_t)(se + 32) * TT + (jt_) + sc);           \
  } while (0)

#define WRITE_STAGE(set_, t_) do {                                             \
    *(uint4*)&vt[set_][t_][se * 64 + sc] = st0;                                \
    *(uint4*)&vt[set_][t_][(se + 32) * 64 + sc] = st1;                         \
  } while (0)

  // prologue: stage tiles 0 and 1 into set 0
  ISSUE_STAGE(0);  WRITE_STAGE(0, 0);
  ISSUE_STAGE(64); WRITE_STAGE(0, 1);
  __syncthreads();

  float qv[4];
#pragma unroll
  for (int f = 0; f < 4; f++) qv[f] = Q[bh * TT + q0 + w * 64 + f * 16 + l16];

  f32x4 acc[4][4];
  f32x4 accd[4];
#pragma unroll
  for (int f = 0; f < 4; f++) {
    accd[f] = (f32x4){0.f, 0.f, 0.f, 0.f};
#pragma unroll
    for (int c = 0; c < 4; c++) acc[f][c] = (f32x4){0.f, 0.f, 0.f, 0.f};
  }
  short8 onesbits = {0x3F80, 0x3F80, 0x3F80, 0x3F80, 0x3F80, 0x3F80, 0x3F80, 0x3F80};
  const bf16x8 ones = __builtin_bit_cast(bf16x8, onesbits);

#define TILE(set_, t_, jt_) do {                                               \
    _Pragma("unroll") for (int kk = 0; kk < 2; kk++) {                         \
      bf16x8 vf[4];                                                            \
      _Pragma("unroll") for (int c = 0; c < 4; c++) {                          \
        const int e = c * 16 + l16;                                            \
        vf[c] = *(const bf16x8*)&vt[set_][t_][e * 64 +                         \
                    (((kk * 4 + lhi) ^ (e & 7)) << 3)];                        \
      }                                                                        \
      const int jb = (jt_) + kk * 32 + lhi * 8;                                \
      float4 ka = *(const float4*)&ks[jb];                                     \
      float4 kb2 = *(const float4*)&ks[jb + 4];                                \
      float4 ca = *(const float4*)&cs[jb];                                     \
      float4 cb2 = *(const float4*)&cs[jb + 4];                                \
      float kv8[8] = {ka.x, ka.y, ka.z, ka.w, kb2.x, kb2.y, kb2.z, kb2.w};     \
      float cv8[8] = {ca.x, ca.y, ca.z, ca.w, cb2.x, cb2.y, cb2.z, cb2.w};     \
      _Pragma("unroll") for (int f = 0; f < 4; f++) {                          \
        bf16x8 pa;                                                             \
        _Pragma("unroll") for (int i = 0; i < 8; i++)                          \
          pa[i] = (__bf16)__builtin_amdgcn_exp2f(fmaf(qv[f], kv8[i], cv8[i])); \
        accd[f] = __builtin_amdgcn_mfma_f32_16x16x32_bf16(pa, ones, accd[f], 0, 0, 0); \
        _Pragma("unroll") for (int c = 0; c < 4; c++)                          \
          acc[f][c] = __builtin_amdgcn_mfma_f32_16x16x32_bf16(pa, vf[c], acc[f][c], 0, 0, 0); \
      }                                                                        \
    }                                                                          \
  } while (0)

  int p = 0;
  for (int jp = 0; jp < TT; jp += 128) {
    const bool more = (jp + 128) < TT;
    if (more) ISSUE_STAGE(jp + 128);        // issue-early tile A of next set

    __builtin_amdgcn_s_setprio(1);
    TILE(p, 0, jp);
    __builtin_amdgcn_s_setprio(0);

    if (more) {
      WRITE_STAGE(p ^ 1, 0);                // write-late tile A
      ISSUE_STAGE(jp + 192);                // issue-early tile B of next set
    }

    __builtin_amdgcn_s_setprio(1);
    TILE(p, 1, jp + 64);
    __builtin_amdgcn_s_setprio(0);

    if (more) WRITE_STAGE(p ^ 1, 1);        // write-late tile B
    __syncthreads();
    p ^= 1;
  }
#undef ISSUE_STAGE
#undef WRITE_STAGE
#undef TILE

#pragma unroll
  for (int f = 0; f < 4; f++) {
#pragma unroll
    for (int r = 0; r < 4; r++) {
      const float rinv = 1.f / accd[f][r];
      const int qrow = q0 + w * 64 + f * 16 + lhi * 4 + r;
      const size_t base = ((size_t)(b * TT + qrow)) * EE + h * DD + l16;
#pragma unroll
      for (int c = 0; c < 4; c++)
        hr[base + c * 16] = f2bf(acc[f][c][r] * rinv);
    }
  }
}

// ---------------- Kernel 4: out = hr @ Wvm + x  (R11 verbatim) -------------
__global__ __launch_bounds__(256, 2) void k_merge(
    const ushort* __restrict__ hr, const ushort* __restrict__ Wmt,
    const float* __restrict__ x, float* __restrict__ out) {
  const int fid = blockIdx.y * 4 + blockIdx.x;   // dispatch order (x fastest)
  const int xcd = fid & 7, idx = fid >> 3;
  const int n0 = (idx & 3) * 128;
  const int m0 = (xcd * 16 + (idx >> 2)) * 128;
  const int tid = threadIdx.x;
  const int w = tid >> 6, l = tid & 63;
  const int l16 = l & 15, lhi = l >> 4;
  const int wm = w >> 1, wn = w & 1;

  __shared__ ushort As[2][128 * 72];
  __shared__ ushort Bs[2][128 * 72];
  f32x4 acc[4][4];
#pragma unroll
  for (int i = 0; i < 4; i++)
#pragma unroll
    for (int j = 0; j < 4; j++) acc[i][j] = (f32x4){0.f, 0.f, 0.f, 0.f};

  const int row = tid >> 1, half = tid & 1;
  const ushort* sa0 = hr + (size_t)(m0 + row) * EE + half * 32;
  const ushort* sb0 = Wmt + (size_t)(n0 + row) * EE + half * 32;

  {
    uint4* da = (uint4*)&As[0][row * 72 + half * 32];
    uint4* db = (uint4*)&Bs[0][row * 72 + half * 32];
#pragma unroll
    for (int i = 0; i < 4; i++) da[i] = *(const uint4*)(sa0 + i * 8);
#pragma unroll
    for (int i = 0; i < 4; i++) db[i] = *(const uint4*)(sb0 + i * 8);
  }
  __syncthreads();

  int p = 0;
  for (int k0 = 0; k0 < EE; k0 += 64) {
    const bool more = (k0 + 64) < EE;
    uint4 pa[4], pb[4];
    if (more) {
#pragma unroll
      for (int i = 0; i < 4; i++) pa[i] = *(const uint4*)(sa0 + k0 + 64 + i * 8);
#pragma unroll
      for (int i = 0; i < 4; i++) pb[i] = *(const uint4*)(sb0 + k0 + 64 + i * 8);
    }
#pragma unroll
    for (int kk = 0; kk < 2; kk++) {
      bf16x8 af[4], bfr[4];
#pragma unroll
      for (int mi = 0; mi < 4; mi++)
        af[mi] = *(const bf16x8*)&As[p][(wm * 64 + mi * 16 + l16) * 72 + kk * 32 + lhi * 8];
#pragma unroll
      for (int ni = 0; ni < 4; ni++)
        bfr[ni] = *(const bf16x8*)&Bs[p][(wn * 64 + ni * 16 + l16) * 72 + kk * 32 + lhi * 8];
#pragma unroll
      for (int mi = 0; mi < 4; mi++)
#pragma unroll
        for (int ni = 0; ni < 4; ni++)
          acc[mi][ni] = __builtin_amdgcn_mfma_f32_16x16x32_bf16(af[mi], bfr[ni], acc[mi][ni], 0, 0, 0);
    }
    if (more) {
      uint4* da = (uint4*)&As[p ^ 1][row * 72 + half * 32];
      uint4* db = (uint4*)&Bs[p ^ 1][row * 72 + half * 32];
#pragma unroll
      for (int i = 0; i < 4; i++) da[i] = pa[i];
#pragma unroll
      for (int i = 0; i < 4; i++) db[i] = pb[i];
    }
    __syncthreads();
    p ^= 1;
  }

#pragma unroll
  for (int mi = 0; mi < 4; mi++) {
#pragma unroll
    for (int r = 0; r < 4; r++) {
      const int grow = m0 + wm * 64 + mi * 16 + lhi * 4 + r;
#pragma unroll
      for (int ni = 0; ni < 4; ni++) {
        const int gcol = n0 + wn * 64 + ni * 16 + l16;
        size_t idx2 = (size_t)grow * EE + gcol;
        out[idx2] = acc[mi][ni][r] + x[idx2];
      }
    }
  }
}

// ---------------- launch ----------------------------------------------------
extern "C" void kernel_launch(void* const* d_in, const int* in_sizes, int n_in,
                              void* d_out, int out_size, void* d_ws, size_t ws_size,
                              hipStream_t stream) {
  const float* x  = (const float*)d_in[0];
  const float* Wq = (const float*)d_in[1];
  const float* Wk = (const float*)d_in[2];
  const float* Wv = (const float*)d_in[3];
  const float* Wm = (const float*)d_in[4];
  float* out = (float*)d_out;

  char* ws = (char*)d_ws;
  float*  Qp   = (float*)(ws);
  float*  Kp   = (float*)(ws + 524288);
  ushort* hrp  = (ushort*)(ws + 1048576);
  ushort* xnt  = (ushort*)(ws + 17825792);
  ushort* Wvmt = (ushort*)(ws + 34603008);

  k_lnt<<<256, 1024, 0, stream>>>(x, Wq, Wk, Qp, Kp, xnt);
  k_wvm<<<EE, 256, 0, stream>>>(Wv, Wm, Wvmt);
  k_attn<<<512, 256, 0, stream>>>(Qp, Kp, xnt, hrp);
  k_merge<<<dim3(EE / 128, (8 * TT) / 128), 256, 0, stream>>>(hrp, Wvmt, x, out);
}